// Round 14
// baseline (5092.141 us; speedup 1.0000x reference)
//
#include <hip/hip_runtime.h>
#include <hip/hip_bf16.h>
#include <stdint.h>

#define UNITS 400
#define GATES 1600
#define TLEN  1000
#define BATCH 64

#define NBLK 8         // blocks per group (weight slices)
#define NGRP 16        // groups; blockIdx = j*16+gr -> all 8 j-blocks share XCD gr%8
#define BPG  4         // batches per group  (THE change vs r8: 2 -> 4)
#define UPB  50        // units per block
#define CPB  200       // cols per block
#define KK   10        // k-split
#define KCH  40        // k rows per z-thread

// d_ws layout
#define WBUF_OFF  0
#define WBUF_SZ   (NBLK*UNITS*CPB*4)                 // 2,560,000 (f32)
#define HBUF_OFF  (WBUF_OFF + WBUF_SZ)
#define HBUF_SZ   (2*BATCH*UNITS*8)                  //   409,600 (u64 {tag,val})
#define PART_OFF  (HBUF_OFF + HBUF_SZ)
#define PART_SZ   (NGRP*NBLK*BPG*3*TLEN*4)           // 6,144,000
#define WS_FULL   ((size_t)PART_OFF + PART_SZ)

#define SPIN_CAP (1 << 20)   // watchdog: stall -> loud absmax fail, not a hang

__device__ __forceinline__ float sigmoid_(float x) {
    return 1.0f / (1.0f + __expf(-x));
}
__device__ __forceinline__ float tanh_(float x) {
    return 1.0f - 2.0f / (__expf(2.0f * x) + 1.0f);
}

// ---- one-time reorder: wbuf[j][k][c] = W_h[k][(c/50)*400 + j*50 + c%50] ----
__global__ void reorder_w(const float* __restrict__ W_h, float* __restrict__ wbuf) {
    int i = blockIdx.x * 256 + threadIdx.x;
    if (i >= NBLK * UNITS * CPB) return;
    int c = i % CPB;
    int k = (i / CPB) % UNITS;
    int j = i / (CPB * UNITS);
    int col = (c / UPB) * UNITS + j * UPB + (c % UPB);
    wbuf[i] = W_h[k * GATES + col];
}

// ---- main: r8 protocol, BPG=4 intensity, f32 weight stream, 2 syncs/step ----
__global__ __launch_bounds__(512, 1) void lstm_mb(
    const float* __restrict__ x,      // [B,T,3]
    const float* __restrict__ W_x,    // [3,1600]
    const float* __restrict__ bvec,   // [1600]
    const float* __restrict__ p_i,
    const float* __restrict__ p_f,
    const float* __restrict__ p_o,
    const float* __restrict__ W_out,  // [400,3]
    const float* __restrict__ wbuf,
    unsigned long long* __restrict__ hbuf,   // [2][B][U] {tag,val}
    float*       __restrict__ part,          // [NGRP*NBLK][BPG][3][TLEN]
    float*       __restrict__ out)           // (finish_y writes out)
{
    const int gr  = blockIdx.x % NGRP;   // XCD-local heuristic (perf only)
    const int j   = blockIdx.x / NGRP;
    const int tid = threadIdx.x;

    __shared__ float hsh[BPG][UNITS];          //  6.4 KB
    __shared__ float zpart[KK][BPG][CPB];      // 32.0 KB
    __shared__ float wosh[UPB][3];
    __shared__ float xsh[BPG][4];

    const float* wslice = wbuf + (size_t)j * UNITS * CPB;

    // ---- roles ----
    const int kk = tid / 50, cq = tid % 50;       // z-role: tid < 500
    const bool zrole = (tid < KK * 50);
    const int k0 = kk * KCH;

    const int gb = tid / UPB, gu = tid % UPB;     // gate-role: tid < 200
    const bool grole = (tid < BPG * UPB);

    const int  idx = tid - 150;                   // poll-role: 350 threads
    const bool prole = (tid >= 150) && (idx < UNITS - UPB);
    const int  pu = idx + (idx >= j * UPB ? UPB : 0);

    const bool yrole = (tid >= 500);              // 12 threads: y-partial + x-stage
    const int yi = tid - 500;                     // 0..11
    const int yb = yi / 3, yf = yi % 3;

    // ---- gate-thread hoists ----
    int unit = 0, batch = 0;
    float wxr[3][4], bb[4];
    float piu = 0.f, pfu = 0.f, pou = 0.f, cc = 0.f;
    if (grole) {
        unit  = j * UPB + gu;
        batch = gr * BPG + gb;
        #pragma unroll
        for (int g = 0; g < 4; ++g) {
            const int gcol = g * UNITS + unit;
            wxr[0][g] = W_x[0 * GATES + gcol];
            wxr[1][g] = W_x[1 * GATES + gcol];
            wxr[2][g] = W_x[2 * GATES + gcol];
            bb[g]     = bvec[gcol];
        }
        piu = p_i[unit]; pfu = p_f[unit]; pou = p_o[unit];
    }
    if (tid < UPB * 3) wosh[tid / 3][tid % 3] = W_out[(j * UPB + tid / 3) * 3 + (tid % 3)];

    // ---- state init ----
    if (tid < UNITS) {
        #pragma unroll
        for (int b = 0; b < BPG; ++b) hsh[b][tid] = 0.f;
    }
    __syncthreads();

#define FMA4(A, s, W) \
    A.x = fmaf(s, W.x, A.x); A.y = fmaf(s, W.y, A.y); \
    A.z = fmaf(s, W.z, A.z); A.w = fmaf(s, W.w, A.w);

    for (int t = 0; t < TLEN; ++t) {
        const int p = t & 1;

        // ================= A: z-partials (16 FMA per weight load) / y(t-1) / x ==
        if (zrole) {
            float4 A0 = {0,0,0,0}, A1 = A0, A2 = A0, A3 = A0;
            #pragma unroll
            for (int ro = 0; ro < KCH; ro += 4) {
                const float* wp = wslice + (size_t)(k0 + ro) * CPB + (cq << 2);
                const float4 w0 = *(const float4*)(wp);
                const float4 w1 = *(const float4*)(wp + CPB);
                const float4 w2 = *(const float4*)(wp + 2 * CPB);
                const float4 w3 = *(const float4*)(wp + 3 * CPB);
                const float4 h0 = *(const float4*)&hsh[0][k0 + ro];
                const float4 h1 = *(const float4*)&hsh[1][k0 + ro];
                const float4 h2 = *(const float4*)&hsh[2][k0 + ro];
                const float4 h3 = *(const float4*)&hsh[3][k0 + ro];
                FMA4(A0, h0.x, w0) FMA4(A0, h0.y, w1) FMA4(A0, h0.z, w2) FMA4(A0, h0.w, w3)
                FMA4(A1, h1.x, w0) FMA4(A1, h1.y, w1) FMA4(A1, h1.z, w2) FMA4(A1, h1.w, w3)
                FMA4(A2, h2.x, w0) FMA4(A2, h2.y, w1) FMA4(A2, h2.z, w2) FMA4(A2, h2.w, w3)
                FMA4(A3, h3.x, w0) FMA4(A3, h3.y, w1) FMA4(A3, h3.z, w2) FMA4(A3, h3.w, w3)
            }
            *(float4*)&zpart[kk][0][cq << 2] = A0;
            *(float4*)&zpart[kk][1][cq << 2] = A1;
            *(float4*)&zpart[kk][2][cq << 2] = A2;
            *(float4*)&zpart[kk][3][cq << 2] = A3;
        } else if (yrole) {
            // x stage for this step
            xsh[yb][yf] = x[((size_t)(gr * BPG + yb) * TLEN + t) * 3 + yf];
            if (t > 0) {
                // y partial for step t-1 (hsh holds that step's h) — ALL blocks
                float s = 0.f;
                #pragma unroll
                for (int u = 0; u < UPB; ++u)
                    s += hsh[yb][j * UPB + u] * wosh[u][yf];
                part[(((size_t)(gr * NBLK + j) * BPG + yb) * 3 + yf) * TLEN + (t - 1)] = s;
            }
        }
        __syncthreads();   // zpart + xsh ready; hsh reads done

        // ================= B: fused reduce + gates + publish (tid<200) ==========
        if (grole) {
            const float x0 = xsh[gb][0], x1 = xsh[gb][1], x2 = xsh[gb][2];
            float s[4];
            #pragma unroll
            for (int g = 0; g < 4; ++g) {
                float acc = fmaf(x0, wxr[0][g],
                            fmaf(x1, wxr[1][g],
                            fmaf(x2, wxr[2][g], bb[g])));
                #pragma unroll
                for (int q = 0; q < KK; ++q) acc += zpart[q][gb][g * UPB + gu];
                s[g] = acc;
            }
            const float ig = sigmoid_(fmaf(piu, cc, s[0]));
            const float fg = sigmoid_(fmaf(pfu, cc, s[1]));
            const float gg = tanh_(s[2]);
            const float cn = fmaf(fg, cc, ig * gg);
            const float og = sigmoid_(fmaf(pou, cn, s[3]));
            const float hn = og * tanh_(cn);
            cc = cn;
            hsh[gb][unit] = hn;    // own slice locally
            const unsigned long long pkt =
                ((unsigned long long)(unsigned)(t + 1) << 32) |
                (unsigned long long)__float_as_uint(hn);
            __hip_atomic_store(&hbuf[(size_t)p * BATCH * UNITS + (size_t)batch * UNITS + unit],
                               pkt, __ATOMIC_RELAXED, __HIP_MEMORY_SCOPE_AGENT);
        }

        // ================= C: poll remote slices (overlaps B) ===================
        if (prole) {
            const unsigned want = (unsigned)(t + 1);
            const size_t base = (size_t)p * BATCH * UNITS
                              + (size_t)(gr * BPG) * UNITS + pu;
            unsigned long long v0, v1, v2, v3;
            int guard = 0;
            for (;;) {
                v0 = __hip_atomic_load(&hbuf[base + 0 * UNITS], __ATOMIC_RELAXED, __HIP_MEMORY_SCOPE_AGENT);
                v1 = __hip_atomic_load(&hbuf[base + 1 * UNITS], __ATOMIC_RELAXED, __HIP_MEMORY_SCOPE_AGENT);
                v2 = __hip_atomic_load(&hbuf[base + 2 * UNITS], __ATOMIC_RELAXED, __HIP_MEMORY_SCOPE_AGENT);
                v3 = __hip_atomic_load(&hbuf[base + 3 * UNITS], __ATOMIC_RELAXED, __HIP_MEMORY_SCOPE_AGENT);
                const unsigned ok =
                    ((unsigned)(v0 >> 32) == want) & ((unsigned)(v1 >> 32) == want) &
                    ((unsigned)(v2 >> 32) == want) & ((unsigned)(v3 >> 32) == want);
                if (ok) break;
                if (++guard > SPIN_CAP) break;   // watchdog
                __builtin_amdgcn_s_sleep(2);
            }
            hsh[0][pu] = __uint_as_float((unsigned)v0);
            hsh[1][pu] = __uint_as_float((unsigned)v1);
            hsh[2][pu] = __uint_as_float((unsigned)v2);
            hsh[3][pu] = __uint_as_float((unsigned)v3);
        }
        __syncthreads();   // hsh = h_{t+1} complete
    }

    // ---- epilogue: y partial for final step ----
    if (yrole) {
        float s = 0.f;
        #pragma unroll
        for (int u = 0; u < UPB; ++u)
            s += hsh[yb][j * UPB + u] * wosh[u][yf];
        part[(((size_t)(gr * NBLK + j) * BPG + yb) * 3 + yf) * TLEN + (TLEN - 1)] = s;
    }
#undef FMA4
}

// ---- post-kernel: out[b][t][f] = b_out[f] + sum_j part[gr][j][gb][f][t] ----
__global__ void finish_y(const float* __restrict__ part,
                         const float* __restrict__ b_out,
                         float* __restrict__ out) {
    int i = blockIdx.x * 256 + threadIdx.x;
    if (i >= BATCH * TLEN * 3) return;
    const int f = i % 3;
    const int bt = i / 3;
    const int t = bt % TLEN;
    const int b = bt / TLEN;
    const int gr = b / BPG, gb = b % BPG;
    float s = b_out[f];
    #pragma unroll
    for (int j = 0; j < NBLK; ++j)
        s += part[(((size_t)(gr * NBLK + j) * BPG + gb) * 3 + f) * TLEN + t];
    out[i] = s;
}

// ---- fallback: proven round-1 single-block-per-batch kernel ----
__global__ __launch_bounds__(512) void lstm_fused_fb(
    const float* __restrict__ x, const float* __restrict__ W_x,
    const float* __restrict__ W_h, const float* __restrict__ bvec,
    const float* __restrict__ p_i, const float* __restrict__ p_f,
    const float* __restrict__ p_o, const float* __restrict__ W_out,
    const float* __restrict__ b_out, float* __restrict__ out)
{
    const int b = blockIdx.x, tid = threadIdx.x;
    const int lane = tid & 63, wv = tid >> 6;
    __shared__ float hsh[UNITS], csh[UNITS], zsh[GATES], xb[3], red[8][3];
    const float4* Wh4 = (const float4*)W_h;
    const int g = tid;
    float4 wx0, wx1, wx2, bb;
    if (g < GATES/4) {
        const float4* Wx4 = (const float4*)W_x;
        wx0 = Wx4[0*400 + g]; wx1 = Wx4[1*400 + g]; wx2 = Wx4[2*400 + g];
        bb  = ((const float4*)bvec)[g];
    }
    float piu=0.f,pfu=0.f,pou=0.f,wo0=0.f,wo1=0.f,wo2=0.f;
    if (tid < UNITS) {
        piu=p_i[tid]; pfu=p_f[tid]; pou=p_o[tid];
        wo0=W_out[tid*3]; wo1=W_out[tid*3+1]; wo2=W_out[tid*3+2];
        hsh[tid]=0.f; csh[tid]=0.f;
    }
    const float bo = (tid<3)?b_out[tid]:0.f;
    const float* xrow = x + (size_t)b*TLEN*3;
    float* orow = out + (size_t)b*TLEN*3;
    for (int t=0;t<TLEN;++t){
        if (tid<3) xb[tid]=xrow[t*3+tid];
        __syncthreads();
        const float x0=xb[0],x1=xb[1],x2=xb[2];
        if (g < GATES/4){
            float4 acc;
            acc.x=fmaf(x0,wx0.x,fmaf(x1,wx1.x,fmaf(x2,wx2.x,bb.x)));
            acc.y=fmaf(x0,wx0.y,fmaf(x1,wx1.y,fmaf(x2,wx2.y,bb.y)));
            acc.z=fmaf(x0,wx0.z,fmaf(x1,wx1.z,fmaf(x2,wx2.z,bb.z)));
            acc.w=fmaf(x0,wx0.w,fmaf(x1,wx1.w,fmaf(x2,wx2.w,bb.w)));
            const float4* wp=Wh4+g;
            #pragma unroll 8
            for(int k=0;k<UNITS;++k){
                const float hk=hsh[k]; const float4 w=wp[(size_t)k*400];
                acc.x=fmaf(hk,w.x,acc.x); acc.y=fmaf(hk,w.y,acc.y);
                acc.z=fmaf(hk,w.z,acc.z); acc.w=fmaf(hk,w.w,acc.w);
            }
            ((float4*)zsh)[g]=acc;
        }
        __syncthreads();
        float s0=0.f,s1=0.f,s2=0.f;
        if (tid<UNITS){
            const float cc=csh[tid];
            const float zi=zsh[tid],zf=zsh[tid+UNITS],zg=zsh[tid+2*UNITS],zo=zsh[tid+3*UNITS];
            const float ig=sigmoid_(fmaf(piu,cc,zi));
            const float fg=sigmoid_(fmaf(pfu,cc,zf));
            const float gg=tanh_(zg);
            const float cn=fmaf(fg,cc,ig*gg);
            const float og=sigmoid_(fmaf(pou,cn,zo));
            const float hn=og*tanh_(cn);
            csh[tid]=cn; hsh[tid]=hn;
            s0=hn*wo0; s1=hn*wo1; s2=hn*wo2;
        }
        #pragma unroll
        for(int off=32;off;off>>=1){
            s0+=__shfl_down(s0,off); s1+=__shfl_down(s1,off); s2+=__shfl_down(s2,off);
        }
        if(lane==0){red[wv][0]=s0;red[wv][1]=s1;red[wv][2]=s2;}
        __syncthreads();
        if(tid<3){
            float r=bo;
            #pragma unroll
            for(int w2=0;w2<8;++w2) r+=red[w2][tid];
            orow[t*3+tid]=r;
        }
    }
}

extern "C" void kernel_launch(void* const* d_in, const int* in_sizes, int n_in,
                              void* d_out, int out_size, void* d_ws, size_t ws_size,
                              hipStream_t stream) {
    const float* x     = (const float*)d_in[0];
    const float* W_x   = (const float*)d_in[1];
    const float* W_h   = (const float*)d_in[2];
    const float* b     = (const float*)d_in[3];
    const float* p_i   = (const float*)d_in[4];
    const float* p_f   = (const float*)d_in[5];
    const float* p_o   = (const float*)d_in[6];
    const float* W_out = (const float*)d_in[7];
    const float* b_out = (const float*)d_in[8];
    float* out = (float*)d_out;

    if (ws_size < WS_FULL) {
        lstm_fused_fb<<<BATCH, 512, 0, stream>>>(x, W_x, W_h, b, p_i, p_f, p_o,
                                                 W_out, b_out, out);
        return;
    }

    uint8_t* ws = (uint8_t*)d_ws;
    float* wbuf = (float*)(ws + WBUF_OFF);
    unsigned long long* hbuf = (unsigned long long*)(ws + HBUF_OFF);
    float* part = (float*)(ws + PART_OFF);

    hipMemsetAsync(hbuf, 0, HBUF_SZ, stream);    // kill stale tags (graph replay)
    reorder_w<<<(NBLK * UNITS * CPB + 255) / 256, 256, 0, stream>>>(W_h, wbuf);
    lstm_mb<<<NGRP * NBLK, 512, 0, stream>>>(x, W_x, b, p_i, p_f, p_o,
                                             W_out, wbuf, hbuf, part, out);
    finish_y<<<(BATCH * TLEN * 3 + 255) / 256, 256, 0, stream>>>(part, b_out, out);
}

// Round 15
// 4787.733 us; speedup vs baseline: 1.0636x; 1.0636x over previous
//
#include <hip/hip_runtime.h>
#include <hip/hip_bf16.h>
#include <stdint.h>

#define UNITS 400
#define GATES 1600
#define TLEN  1000
#define BATCH 64

#define NBLK 8         // blocks per group = weight slices
#define NGRP 32        // groups; blockIdx = j*32+gr -> group XCD-local
#define BPG  2         // batches per group
#define UPB  50        // units per block/slice
#define CPB  200       // cols per block
#define NSL  8         // slices

// d_ws layout
#define WBUF_OFF  0
#define WBUF_SZ   (NBLK*UNITS*CPB*4)                 // 2,560,000 (f32)
#define HBUF_OFF  (WBUF_OFF + WBUF_SZ)
#define HBUF_SZ   (2*BATCH*UNITS*8)                  //   409,600 (u64 {tag,val})
#define PART_OFF  (HBUF_OFF + HBUF_SZ)
#define PART_SZ   (NGRP*NBLK*BPG*3*TLEN*4)           // 6,144,000
#define WS_FULL   ((size_t)PART_OFF + PART_SZ)

#define SPIN_CAP (1 << 18)   // watchdog: stall -> loud absmax fail, not a hang

__device__ __forceinline__ float sigmoid_(float x) {
    return 1.0f / (1.0f + __expf(-x));
}
__device__ __forceinline__ float tanh_(float x) {
    return 1.0f - 2.0f / (__expf(2.0f * x) + 1.0f);
}

// ---- one-time reorder: wbuf[j][k][c] = W_h[k][(c/50)*400 + j*50 + c%50] ----
__global__ void reorder_w(const float* __restrict__ W_h, float* __restrict__ wbuf) {
    int i = blockIdx.x * 256 + threadIdx.x;
    if (i >= NBLK * UNITS * CPB) return;
    int c = i % CPB;
    int k = (i / CPB) % UNITS;
    int j = i / (CPB * UNITS);
    int col = (c / UPB) * UNITS + j * UPB + (c % UPB);
    wbuf[i] = W_h[k * GATES + col];
}

// ---- main: slice-granular dependency, 1 barrier/step, tag-in-data exchange ----
__global__ __launch_bounds__(512, 1) void lstm_mb(
    const float* __restrict__ x,      // [B,T,3]
    const float* __restrict__ W_x,    // [3,1600]
    const float* __restrict__ bvec,   // [1600]
    const float* __restrict__ p_i,
    const float* __restrict__ p_f,
    const float* __restrict__ p_o,
    const float* __restrict__ W_out,  // [400,3]
    const float* __restrict__ wbuf,
    unsigned long long* __restrict__ hbuf,   // [2][B][U] {tag,val}
    float*       __restrict__ part,          // [NGRP*NBLK][BPG][3][TLEN]
    float*       __restrict__ out)           // (finish_y writes out)
{
    const int gr  = blockIdx.x % NGRP;   // XCD-local heuristic (perf only)
    const int j   = blockIdx.x / NGRP;   // weight slice owned by this block
    const int tid = threadIdx.x;

    __shared__ float hsh[2][BPG][UNITS];        //  6.4 KB: h_t at parity t&1
    __shared__ float zpart[2][NSL][BPG][CPB];   // 25.6 KB: parity-dbuf partials
    __shared__ float wosh[UPB][3];
    __shared__ unsigned cnt[2][NSL];            // slice-ready counters (monotone)

    const float* wslice = wbuf + (size_t)j * UNITS * CPB;

    // ---- roles (disjoint!) ----
    const bool zrole = (tid < 400);
    const int  kk = tid / UPB, cq = tid % UPB;   // slice, col-quad
    const int  zunit = kk * UPB + cq;            // the unit this z-thread polls
    const unsigned TGT = (kk == j) ? 100u : 50u; // per-round bump total for slice

    const bool grole = (tid >= 400) && (tid < 500);
    const int  gb = (tid - 400) / UPB, gu = (tid - 400) % UPB;

    const bool yrole = (tid >= 500) && (tid < 506);
    const int  yb = (tid - 500) / 3, yf = (tid - 500) % 3;

    // ---- gate-thread hoists ----
    int unit = 0, batch = 0;
    float wxr[3][4], bb[4];
    float piu = 0.f, pfu = 0.f, pou = 0.f, cc = 0.f;
    if (grole) {
        unit  = j * UPB + gu;
        batch = gr * BPG + gb;
        #pragma unroll
        for (int g = 0; g < 4; ++g) {
            const int gcol = g * UNITS + unit;
            wxr[0][g] = W_x[0 * GATES + gcol];
            wxr[1][g] = W_x[1 * GATES + gcol];
            wxr[2][g] = W_x[2 * GATES + gcol];
            bb[g]     = bvec[gcol];
        }
        piu = p_i[unit]; pfu = p_f[unit]; pou = p_o[unit];
    }
    if (tid < UPB * 3) wosh[tid / 3][tid % 3] = W_out[(j * UPB + tid / 3) * 3 + (tid % 3)];

    // ---- init: h_0 = 0 at parity 0; counters pre-credited for round 1 ----
    if (tid < UNITS) { hsh[0][0][tid] = 0.f; hsh[0][1][tid] = 0.f; }
    if (tid < 2 * NSL) {
        const int qq = tid / NSL, ss = tid % NSL;
        cnt[qq][ss] = (qq == 0) ? ((ss == j) ? 100u : 50u) : 0u;
    }
    __syncthreads();

    for (int t = 0; t < TLEN; ++t) {
        const int q = t & 1;
        const unsigned r = (unsigned)((t - q) / 2 + 1);   // round index for parity q

        if (zrole) {
            // ---- poll own 2 packets of slice kk (remote slices only) ----
            if (t > 0 && kk != j) {
                const unsigned want = (unsigned)t;
                const size_t base = (size_t)q * BATCH * UNITS
                                  + (size_t)(gr * BPG) * UNITS + zunit;
                unsigned long long v0, v1;
                int gd = 0;
                for (;;) {
                    v0 = __hip_atomic_load(&hbuf[base], __ATOMIC_RELAXED, __HIP_MEMORY_SCOPE_AGENT);
                    v1 = __hip_atomic_load(&hbuf[base + UNITS], __ATOMIC_RELAXED, __HIP_MEMORY_SCOPE_AGENT);
                    if ((unsigned)(v0 >> 32) == want && (unsigned)(v1 >> 32) == want) break;
                    if (++gd > SPIN_CAP) break;   // watchdog
                    __builtin_amdgcn_s_sleep(1);
                }
                hsh[q][0][zunit] = __uint_as_float((unsigned)v0);
                hsh[q][1][zunit] = __uint_as_float((unsigned)v1);
                __hip_atomic_fetch_add(&cnt[q][kk], 1u,
                                       __ATOMIC_RELEASE, __HIP_MEMORY_SCOPE_WORKGROUP);
            }
            // ---- wait: whole slice kk present (49 peers + self, or gates) ----
            {
                const unsigned tgt = TGT * r;
                int gd = 0;
                while (__hip_atomic_load(&cnt[q][kk], __ATOMIC_ACQUIRE,
                                         __HIP_MEMORY_SCOPE_WORKGROUP) < tgt) {
                    if (++gd > SPIN_CAP) break;   // watchdog
                    __builtin_amdgcn_s_sleep(1);
                }
            }
            // ---- z over slice kk: 50 rows x 4 cols x 2 batches = 400 FMA ----
            const int k0 = kk * UPB;
            float4 A0 = {0, 0, 0, 0}, A1 = A0;
            #pragma unroll
            for (int i = 0; i < UPB; i += 2) {
                const float* wp = wslice + (size_t)(k0 + i) * CPB + (cq << 2);
                const float4 w0 = *(const float4*)(wp);
                const float4 w1 = *(const float4*)(wp + CPB);
                const float2 h0 = *(const float2*)&hsh[q][0][k0 + i];
                const float2 h1 = *(const float2*)&hsh[q][1][k0 + i];
                A0.x = fmaf(h0.x, w0.x, A0.x); A0.y = fmaf(h0.x, w0.y, A0.y);
                A0.z = fmaf(h0.x, w0.z, A0.z); A0.w = fmaf(h0.x, w0.w, A0.w);
                A0.x = fmaf(h0.y, w1.x, A0.x); A0.y = fmaf(h0.y, w1.y, A0.y);
                A0.z = fmaf(h0.y, w1.z, A0.z); A0.w = fmaf(h0.y, w1.w, A0.w);
                A1.x = fmaf(h1.x, w0.x, A1.x); A1.y = fmaf(h1.x, w0.y, A1.y);
                A1.z = fmaf(h1.x, w0.z, A1.z); A1.w = fmaf(h1.x, w0.w, A1.w);
                A1.x = fmaf(h1.y, w1.x, A1.x); A1.y = fmaf(h1.y, w1.y, A1.y);
                A1.z = fmaf(h1.y, w1.z, A1.z); A1.w = fmaf(h1.y, w1.w, A1.w);
            }
            *(float4*)&zpart[q][kk][0][cq << 2] = A0;
            *(float4*)&zpart[q][kk][1][cq << 2] = A1;
        } else if (grole) {
            // prefetch x_t while z runs (uses L1; consumed after barrier)
            // (loads issued here, values used below)
        } else if (yrole && t > 0) {
            // y for out-row t-1 from h_t (own slice), guarded by slice counter
            const unsigned tgt = 100u * r;
            int gd = 0;
            while (__hip_atomic_load(&cnt[q][j], __ATOMIC_ACQUIRE,
                                     __HIP_MEMORY_SCOPE_WORKGROUP) < tgt) {
                if (++gd > SPIN_CAP) break;
                __builtin_amdgcn_s_sleep(1);
            }
            float s = 0.f;
            #pragma unroll
            for (int u = 0; u < UPB; ++u)
                s += hsh[q][yb][j * UPB + u] * wosh[u][yf];
            part[(((size_t)(gr * NBLK + j) * BPG + yb) * 3 + yf) * TLEN + (t - 1)] = s;
        }

        float xv0 = 0.f, xv1 = 0.f, xv2 = 0.f;
        if (grole) {
            const float* xp = x + ((size_t)batch * TLEN + t) * 3;
            xv0 = xp[0]; xv1 = xp[1]; xv2 = xp[2];
        }
        __syncthreads();   // zpart[q] complete

        // ---- gates: reduce 8 slices + x-proj -> h_{t+1}; publish; bump ----
        if (grole) {
            float s[4];
            #pragma unroll
            for (int g = 0; g < 4; ++g) {
                float acc = fmaf(xv0, wxr[0][g],
                            fmaf(xv1, wxr[1][g],
                            fmaf(xv2, wxr[2][g], bb[g])));
                #pragma unroll
                for (int s8 = 0; s8 < NSL; ++s8)
                    acc += zpart[q][s8][gb][g * UPB + gu];
                s[g] = acc;
            }
            const float ig = sigmoid_(fmaf(piu, cc, s[0]));
            const float fg = sigmoid_(fmaf(pfu, cc, s[1]));
            const float gg = tanh_(s[2]);
            const float cn = fmaf(fg, cc, ig * gg);
            const float og = sigmoid_(fmaf(pou, cn, s[3]));
            const float hn = og * tanh_(cn);
            cc = cn;
            hsh[q ^ 1][gb][unit] = hn;           // own slice locally (next parity)
            const unsigned long long pkt =
                ((unsigned long long)(unsigned)(t + 1) << 32) |
                (unsigned long long)__float_as_uint(hn);
            __hip_atomic_store(&hbuf[(size_t)(q ^ 1) * BATCH * UNITS
                                     + (size_t)batch * UNITS + unit],
                               pkt, __ATOMIC_RELAXED, __HIP_MEMORY_SCOPE_AGENT);
            __hip_atomic_fetch_add(&cnt[q ^ 1][j], 1u,
                                   __ATOMIC_RELEASE, __HIP_MEMORY_SCOPE_WORKGROUP);
        }
    }

    // ---- epilogue: y row TLEN-1 from h_TLEN (parity 0, round 501) ----
    if (yrole) {
        const unsigned tgt = 100u * (unsigned)(TLEN / 2 + 1);
        int gd = 0;
        while (__hip_atomic_load(&cnt[0][j], __ATOMIC_ACQUIRE,
                                 __HIP_MEMORY_SCOPE_WORKGROUP) < tgt) {
            if (++gd > SPIN_CAP) break;
            __builtin_amdgcn_s_sleep(1);
        }
        float s = 0.f;
        #pragma unroll
        for (int u = 0; u < UPB; ++u)
            s += hsh[0][yb][j * UPB + u] * wosh[u][yf];
        part[(((size_t)(gr * NBLK + j) * BPG + yb) * 3 + yf) * TLEN + (TLEN - 1)] = s;
    }
}

// ---- post-kernel: out[b][t][f] = b_out[f] + sum_j part[gr][j][gb][f][t] ----
__global__ void finish_y(const float* __restrict__ part,
                         const float* __restrict__ b_out,
                         float* __restrict__ out) {
    int i = blockIdx.x * 256 + threadIdx.x;
    if (i >= BATCH * TLEN * 3) return;
    const int f = i % 3;
    const int bt = i / 3;
    const int t = bt % TLEN;
    const int b = bt / TLEN;
    const int gr = b / BPG, gb = b % BPG;
    float s = b_out[f];
    #pragma unroll
    for (int j = 0; j < NBLK; ++j)
        s += part[(((size_t)(gr * NBLK + j) * BPG + gb) * 3 + f) * TLEN + t];
    out[i] = s;
}

// ---- fallback: proven round-1 single-block-per-batch kernel ----
__global__ __launch_bounds__(512) void lstm_fused_fb(
    const float* __restrict__ x, const float* __restrict__ W_x,
    const float* __restrict__ W_h, const float* __restrict__ bvec,
    const float* __restrict__ p_i, const float* __restrict__ p_f,
    const float* __restrict__ p_o, const float* __restrict__ W_out,
    const float* __restrict__ b_out, float* __restrict__ out)
{
    const int b = blockIdx.x, tid = threadIdx.x;
    const int lane = tid & 63, wv = tid >> 6;
    __shared__ float hsh[UNITS], csh[UNITS], zsh[GATES], xb[3], red[8][3];
    const float4* Wh4 = (const float4*)W_h;
    const int g = tid;
    float4 wx0, wx1, wx2, bb;
    if (g < GATES/4) {
        const float4* Wx4 = (const float4*)W_x;
        wx0 = Wx4[0*400 + g]; wx1 = Wx4[1*400 + g]; wx2 = Wx4[2*400 + g];
        bb  = ((const float4*)bvec)[g];
    }
    float piu=0.f,pfu=0.f,pou=0.f,wo0=0.f,wo1=0.f,wo2=0.f;
    if (tid < UNITS) {
        piu=p_i[tid]; pfu=p_f[tid]; pou=p_o[tid];
        wo0=W_out[tid*3]; wo1=W_out[tid*3+1]; wo2=W_out[tid*3+2];
        hsh[tid]=0.f; csh[tid]=0.f;
    }
    const float bo = (tid<3)?b_out[tid]:0.f;
    const float* xrow = x + (size_t)b*TLEN*3;
    float* orow = out + (size_t)b*TLEN*3;
    for (int t=0;t<TLEN;++t){
        if (tid<3) xb[tid]=xrow[t*3+tid];
        __syncthreads();
        const float x0=xb[0],x1=xb[1],x2=xb[2];
        if (g < GATES/4){
            float4 acc;
            acc.x=fmaf(x0,wx0.x,fmaf(x1,wx1.x,fmaf(x2,wx2.x,bb.x)));
            acc.y=fmaf(x0,wx0.y,fmaf(x1,wx1.y,fmaf(x2,wx2.y,bb.y)));
            acc.z=fmaf(x0,wx0.z,fmaf(x1,wx1.z,fmaf(x2,wx2.z,bb.z)));
            acc.w=fmaf(x0,wx0.w,fmaf(x1,wx1.w,fmaf(x2,wx2.w,bb.w)));
            const float4* wp=Wh4+g;
            #pragma unroll 8
            for(int k=0;k<UNITS;++k){
                const float hk=hsh[k]; const float4 w=wp[(size_t)k*400];
                acc.x=fmaf(hk,w.x,acc.x); acc.y=fmaf(hk,w.y,acc.y);
                acc.z=fmaf(hk,w.z,acc.z); acc.w=fmaf(hk,w.w,acc.w);
            }
            ((float4*)zsh)[g]=acc;
        }
        __syncthreads();
        float s0=0.f,s1=0.f,s2=0.f;
        if (tid<UNITS){
            const float cc=csh[tid];
            const float zi=zsh[tid],zf=zsh[tid+UNITS],zg=zsh[tid+2*UNITS],zo=zsh[tid+3*UNITS];
            const float ig=sigmoid_(fmaf(piu,cc,zi));
            const float fg=sigmoid_(fmaf(pfu,cc,zf));
            const float gg=tanh_(zg);
            const float cn=fmaf(fg,cc,ig*gg);
            const float og=sigmoid_(fmaf(pou,cn,zo));
            const float hn=og*tanh_(cn);
            csh[tid]=cn; hsh[tid]=hn;
            s0=hn*wo0; s1=hn*wo1; s2=hn*wo2;
        }
        #pragma unroll
        for(int off=32;off;off>>=1){
            s0+=__shfl_down(s0,off); s1+=__shfl_down(s1,off); s2+=__shfl_down(s2,off);
        }
        if(lane==0){red[wv][0]=s0;red[wv][1]=s1;red[wv][2]=s2;}
        __syncthreads();
        if(tid<3){
            float r=bo;
            #pragma unroll
            for(int w2=0;w2<8;++w2) r+=red[w2][tid];
            orow[t*3+tid]=r;
        }
    }
}

extern "C" void kernel_launch(void* const* d_in, const int* in_sizes, int n_in,
                              void* d_out, int out_size, void* d_ws, size_t ws_size,
                              hipStream_t stream) {
    const float* x     = (const float*)d_in[0];
    const float* W_x   = (const float*)d_in[1];
    const float* W_h   = (const float*)d_in[2];
    const float* b     = (const float*)d_in[3];
    const float* p_i   = (const float*)d_in[4];
    const float* p_f   = (const float*)d_in[5];
    const float* p_o   = (const float*)d_in[6];
    const float* W_out = (const float*)d_in[7];
    const float* b_out = (const float*)d_in[8];
    float* out = (float*)d_out;

    if (ws_size < WS_FULL) {
        lstm_fused_fb<<<BATCH, 512, 0, stream>>>(x, W_x, W_h, b, p_i, p_f, p_o,
                                                 W_out, b_out, out);
        return;
    }

    uint8_t* ws = (uint8_t*)d_ws;
    float* wbuf = (float*)(ws + WBUF_OFF);
    unsigned long long* hbuf = (unsigned long long*)(ws + HBUF_OFF);
    float* part = (float*)(ws + PART_OFF);

    hipMemsetAsync(hbuf, 0, HBUF_SZ, stream);    // kill stale tags (graph replay)
    reorder_w<<<(NBLK * UNITS * CPB + 255) / 256, 256, 0, stream>>>(W_h, wbuf);
    lstm_mb<<<NGRP * NBLK, 512, 0, stream>>>(x, W_x, b, p_i, p_f, p_o,
                                             W_out, wbuf, hbuf, part, out);
    finish_y<<<(BATCH * TLEN * 3 + 255) / 256, 256, 0, stream>>>(part, b_out, out);
}

// Round 16
// 3022.673 us; speedup vs baseline: 1.6846x; 1.5839x over previous
//
#include <hip/hip_runtime.h>
#include <hip/hip_bf16.h>
#include <stdint.h>

#define UNITS 400
#define GATES 1600
#define TLEN  1000
#define BATCH 64

#define NBLK 8         // blocks per group (weight slices)
#define NGRP 32        // groups
#define BPG  2         // batches per group
#define UPB  50        // units per block
#define CPB  200       // cols per block
#define KK   10        // k-split
#define KCH  40        // k-chunk -> 40x4 weight regs/thread

// d_ws layout
#define WBUF_OFF  0
#define WBUF_SZ   (NBLK*UNITS*CPB*4)                 // 2,560,000
#define HBUF_OFF  (WBUF_OFF + WBUF_SZ)
#define HBUF_SZ   (2*BATCH*UNITS*8)                  //   409,600 (u64 packets)
#define PART_OFF  (HBUF_OFF + HBUF_SZ)
#define PART_SZ   (NGRP*NBLK*BPG*3*TLEN*4)           // 6,144,000
#define WS_FULL   ((size_t)PART_OFF + PART_SZ)

#define SPIN_CAP (1 << 20)   // watchdog: stall -> loud absmax fail, not a hang

__device__ __forceinline__ float sigmoid_(float x) {
    return 1.0f / (1.0f + __expf(-x));
}
__device__ __forceinline__ float tanh_(float x) {
    return 1.0f - 2.0f / (__expf(2.0f * x) + 1.0f);
}

// ---- one-time weight reorder: wbuf[j][k][c] = W_h[k][(c/UPB)*UNITS + j*UPB + c%UPB] ----
__global__ void reorder_w(const float* __restrict__ W_h, float* __restrict__ wbuf) {
    int i = blockIdx.x * 256 + threadIdx.x;
    if (i >= NBLK * UNITS * CPB) return;
    int c = i % CPB;
    int k = (i / CPB) % UNITS;
    int j = i / (CPB * UNITS);
    int g = c / UPB, u2 = c % UPB;
    int col = g * UNITS + j * UPB + u2;
    wbuf[i] = W_h[k * GATES + col];
}

// ---- main: r8-verbatim — fused gates, tag-in-data exchange, 2 syncs/step ----
__global__ __launch_bounds__(512, 1) void lstm_mb(
    const float* __restrict__ x,      // [B,T,3]
    const float* __restrict__ W_x,    // [3,1600]
    const float* __restrict__ bvec,   // [1600]
    const float* __restrict__ p_i,
    const float* __restrict__ p_f,
    const float* __restrict__ p_o,
    const float* __restrict__ W_out,  // [400,3]
    const float* __restrict__ wbuf,
    unsigned long long* __restrict__ hbuf,   // [2][B][U] {tag,val}
    float*       __restrict__ part,          // [NGRP*NBLK][BPG][3][TLEN]
    float*       __restrict__ out)           // (finish_y writes out)
{
    const int gr  = blockIdx.x % NGRP;   // XCD-local heuristic (perf only)
    const int j   = blockIdx.x / NGRP;
    const int tid = threadIdx.x;

    __shared__ float hsh[BPG][UNITS];          // 3.2 KB
    __shared__ float zpart[KK][BPG][CPB];      // 16 KB
    __shared__ float wosh[UPB][3];
    __shared__ float xsh[BPG][4];

    const float* wslice = wbuf + (size_t)j * UNITS * CPB;

    // ---- roles ----
    const int kk = tid / 50, cq = tid % 50;       // z-role: tid < 500
    const bool zrole = (tid < KK * 50);
    const int k0 = kk * KCH;

    const int gb = tid / UPB, gu = tid % UPB;     // gate-role: tid < 100
    const bool grole = (tid < BPG * UPB);

    const bool prole = (tid < UNITS) && (tid / UPB != j);  // poll-role: skip own slice
    const bool yrole = (tid >= 500) && (tid < 500 + BPG * 3);
    const int yb = (tid - 500) / 3, yf = (tid - 500) % 3;
    const bool xrole = (tid >= 500 + BPG * 3) && (tid < 500 + 2 * BPG * 3);
    const int xb2 = (tid - 500 - BPG * 3) / 3, xf = (tid - 500 - BPG * 3) % 3;

    // ---- register-pinned weight patch: 40x4 floats, opaque to remat ----
    float wr[KCH][4];
    if (zrole) {
        #pragma unroll
        for (int r = 0; r < KCH; ++r) {
            const float4 w = *(const float4*)&wslice[(size_t)(k0 + r) * CPB + cq * 4];
            wr[r][0] = w.x; wr[r][1] = w.y; wr[r][2] = w.z; wr[r][3] = w.w;
        }
        #pragma unroll
        for (int r = 0; r < KCH; ++r) {
            asm volatile("" : "+v"(wr[r][0]), "+v"(wr[r][1]),
                              "+v"(wr[r][2]), "+v"(wr[r][3]));
        }
    }

    // ---- gate-thread hoists ----
    int unit = 0, batch = 0;
    float wxr[3][4], bb[4];
    float piu = 0.f, pfu = 0.f, pou = 0.f, cc = 0.f;
    if (grole) {
        unit  = j * UPB + gu;
        batch = gr * BPG + gb;
        #pragma unroll
        for (int g = 0; g < 4; ++g) {
            const int gcol = g * UNITS + unit;
            wxr[0][g] = W_x[0 * GATES + gcol];
            wxr[1][g] = W_x[1 * GATES + gcol];
            wxr[2][g] = W_x[2 * GATES + gcol];
            bb[g]     = bvec[gcol];
        }
        piu = p_i[unit]; pfu = p_f[unit]; pou = p_o[unit];
    }
    if (tid < UPB * 3) wosh[tid / 3][tid % 3] = W_out[(j * UPB + tid / 3) * 3 + (tid % 3)];

    // ---- state init ----
    if (tid < UNITS) { hsh[0][tid] = 0.f; hsh[1][tid] = 0.f; }
    __syncthreads();

    for (int t = 0; t < TLEN; ++t) {
        const int p = t & 1;

        // ================= A: z-partials (+ x stage, deferred partial-y) ========
        if (zrole) {
            float4 a0 = {0,0,0,0}, a1 = a0;
            #pragma unroll
            for (int ro = 0; ro < KCH; ro += 4) {
                const float4 h0 = *(const float4*)&hsh[0][k0 + ro];
                const float4 h1 = *(const float4*)&hsh[1][k0 + ro];
                #pragma unroll
                for (int dr = 0; dr < 4; ++dr) {
                    const float e0 = (dr==0)?h0.x:(dr==1)?h0.y:(dr==2)?h0.z:h0.w;
                    const float e1 = (dr==0)?h1.x:(dr==1)?h1.y:(dr==2)?h1.z:h1.w;
                    a0.x = fmaf(e0, wr[ro+dr][0], a0.x);
                    a0.y = fmaf(e0, wr[ro+dr][1], a0.y);
                    a0.z = fmaf(e0, wr[ro+dr][2], a0.z);
                    a0.w = fmaf(e0, wr[ro+dr][3], a0.w);
                    a1.x = fmaf(e1, wr[ro+dr][0], a1.x);
                    a1.y = fmaf(e1, wr[ro+dr][1], a1.y);
                    a1.z = fmaf(e1, wr[ro+dr][2], a1.z);
                    a1.w = fmaf(e1, wr[ro+dr][3], a1.w);
                }
            }
            *(float4*)&zpart[kk][0][cq * 4] = a0;
            *(float4*)&zpart[kk][1][cq * 4] = a1;
        } else if (yrole && t > 0) {
            // y partial for step t-1 (hsh holds that step's output h)
            float s = 0.f;
            #pragma unroll
            for (int u = 0; u < UPB; ++u)
                s += hsh[yb][j * UPB + u] * wosh[u][yf];
            part[(((size_t)(gr * NBLK + j) * BPG + yb) * 3 + yf) * TLEN + (t - 1)] = s;
        } else if (xrole) {
            xsh[xb2][xf] = x[((size_t)(gr * BPG + xb2) * TLEN + t) * 3 + xf];
        }
        __syncthreads();   // zpart + xsh ready; hsh reads done

        // ================= B: fused reduce + gates + publish (tid<100) ==========
        if (grole) {
            const float x0 = xsh[gb][0], x1 = xsh[gb][1], x2 = xsh[gb][2];
            float s[4];
            #pragma unroll
            for (int g = 0; g < 4; ++g) {
                float acc = fmaf(x0, wxr[0][g],
                            fmaf(x1, wxr[1][g],
                            fmaf(x2, wxr[2][g], bb[g])));
                #pragma unroll
                for (int q = 0; q < KK; ++q) acc += zpart[q][gb][g * UPB + gu];
                s[g] = acc;
            }
            const float ig = sigmoid_(fmaf(piu, cc, s[0]));
            const float fg = sigmoid_(fmaf(pfu, cc, s[1]));
            const float gg = tanh_(s[2]);
            const float cn = fmaf(fg, cc, ig * gg);
            const float og = sigmoid_(fmaf(pou, cn, s[3]));
            const float hn = og * tanh_(cn);
            cc = cn;
            hsh[gb][unit] = hn;    // own slice locally
            const unsigned long long pkt =
                ((unsigned long long)(unsigned)(t + 1) << 32) |
                (unsigned long long)__float_as_uint(hn);
            __hip_atomic_store(&hbuf[(size_t)p * BATCH * UNITS + (size_t)batch * UNITS + unit],
                               pkt, __ATOMIC_RELAXED, __HIP_MEMORY_SCOPE_AGENT);
        }

        // ================= C: poll remote slices (overlaps B) ===================
        if (prole) {
            const unsigned want = (unsigned)(t + 1);
            const size_t base = (size_t)p * BATCH * UNITS
                              + (size_t)(gr * BPG) * UNITS + tid;
            unsigned long long v0, v1;
            int guard = 0;
            for (;;) {
                v0 = __hip_atomic_load(&hbuf[base],
                                       __ATOMIC_RELAXED, __HIP_MEMORY_SCOPE_AGENT);
                v1 = __hip_atomic_load(&hbuf[base + UNITS],
                                       __ATOMIC_RELAXED, __HIP_MEMORY_SCOPE_AGENT);
                if ((unsigned)(v0 >> 32) == want && (unsigned)(v1 >> 32) == want) break;
                if (++guard > SPIN_CAP) break;   // watchdog: fail loud, not hang
                __builtin_amdgcn_s_sleep(2);
            }
            hsh[0][tid] = __uint_as_float((unsigned)v0);
            hsh[1][tid] = __uint_as_float((unsigned)v1);
        }
        __syncthreads();   // hsh = h_{t+1} complete
    }

    // ---- epilogue: y partial for final step ----
    if (yrole) {
        float s = 0.f;
        #pragma unroll
        for (int u = 0; u < UPB; ++u)
            s += hsh[yb][j * UPB + u] * wosh[u][yf];
        part[(((size_t)(gr * NBLK + j) * BPG + yb) * 3 + yf) * TLEN + (TLEN - 1)] = s;
    }
}

// ---- post-kernel: out[b][t][f] = b_out[f] + sum_j part[gr][j][gb][f][t] ----
__global__ void finish_y(const float* __restrict__ part,
                         const float* __restrict__ b_out,
                         float* __restrict__ out) {
    int i = blockIdx.x * 256 + threadIdx.x;
    if (i >= BATCH * TLEN * 3) return;
    const int f = i % 3;
    const int bt = i / 3;
    const int t = bt % TLEN;
    const int b = bt / TLEN;
    const int gr = b / BPG, gb = b % BPG;
    float s = b_out[f];
    #pragma unroll
    for (int j = 0; j < NBLK; ++j)
        s += part[(((size_t)(gr * NBLK + j) * BPG + gb) * 3 + f) * TLEN + t];
    out[i] = s;
}

// ---- fallback: proven round-1 single-block-per-batch kernel ----
__global__ __launch_bounds__(512) void lstm_fused_fb(
    const float* __restrict__ x, const float* __restrict__ W_x,
    const float* __restrict__ W_h, const float* __restrict__ bvec,
    const float* __restrict__ p_i, const float* __restrict__ p_f,
    const float* __restrict__ p_o, const float* __restrict__ W_out,
    const float* __restrict__ b_out, float* __restrict__ out)
{
    const int b = blockIdx.x, tid = threadIdx.x;
    const int lane = tid & 63, wv = tid >> 6;
    __shared__ float hsh[UNITS], csh[UNITS], zsh[GATES], xb[3], red[8][3];
    const float4* Wh4 = (const float4*)W_h;
    const int g = tid;
    float4 wx0, wx1, wx2, bb;
    if (g < GATES/4) {
        const float4* Wx4 = (const float4*)W_x;
        wx0 = Wx4[0*400 + g]; wx1 = Wx4[1*400 + g]; wx2 = Wx4[2*400 + g];
        bb  = ((const float4*)bvec)[g];
    }
    float piu=0.f,pfu=0.f,pou=0.f,wo0=0.f,wo1=0.f,wo2=0.f;
    if (tid < UNITS) {
        piu=p_i[tid]; pfu=p_f[tid]; pou=p_o[tid];
        wo0=W_out[tid*3]; wo1=W_out[tid*3+1]; wo2=W_out[tid*3+2];
        hsh[tid]=0.f; csh[tid]=0.f;
    }
    const float bo = (tid<3)?b_out[tid]:0.f;
    const float* xrow = x + (size_t)b*TLEN*3;
    float* orow = out + (size_t)b*TLEN*3;
    for (int t=0;t<TLEN;++t){
        if (tid<3) xb[tid]=xrow[t*3+tid];
        __syncthreads();
        const float x0=xb[0],x1=xb[1],x2=xb[2];
        if (g < GATES/4){
            float4 acc;
            acc.x=fmaf(x0,wx0.x,fmaf(x1,wx1.x,fmaf(x2,wx2.x,bb.x)));
            acc.y=fmaf(x0,wx0.y,fmaf(x1,wx1.y,fmaf(x2,wx2.y,bb.y)));
            acc.z=fmaf(x0,wx0.z,fmaf(x1,wx1.z,fmaf(x2,wx2.z,bb.z)));
            acc.w=fmaf(x0,wx0.w,fmaf(x1,wx1.w,fmaf(x2,wx2.w,bb.w)));
            const float4* wp=Wh4+g;
            #pragma unroll 8
            for(int k=0;k<UNITS;++k){
                const float hk=hsh[k]; const float4 w=wp[(size_t)k*400];
                acc.x=fmaf(hk,w.x,acc.x); acc.y=fmaf(hk,w.y,acc.y);
                acc.z=fmaf(hk,w.z,acc.z); acc.w=fmaf(hk,w.w,acc.w);
            }
            ((float4*)zsh)[g]=acc;
        }
        __syncthreads();
        float s0=0.f,s1=0.f,s2=0.f;
        if (tid<UNITS){
            const float cc=csh[tid];
            const float zi=zsh[tid],zf=zsh[tid+UNITS],zg=zsh[tid+2*UNITS],zo=zsh[tid+3*UNITS];
            const float ig=sigmoid_(fmaf(piu,cc,zi));
            const float fg=sigmoid_(fmaf(pfu,cc,zf));
            const float gg=tanh_(zg);
            const float cn=fmaf(fg,cc,ig*gg);
            const float og=sigmoid_(fmaf(pou,cn,zo));
            const float hn=og*tanh_(cn);
            csh[tid]=cn; hsh[tid]=hn;
            s0=hn*wo0; s1=hn*wo1; s2=hn*wo2;
        }
        #pragma unroll
        for(int off=32;off;off>>=1){
            s0+=__shfl_down(s0,off); s1+=__shfl_down(s1,off); s2+=__shfl_down(s2,off);
        }
        if(lane==0){red[wv][0]=s0;red[wv][1]=s1;red[wv][2]=s2;}
        __syncthreads();
        if(tid<3){
            float r=bo;
            #pragma unroll
            for(int w2=0;w2<8;++w2) r+=red[w2][tid];
            orow[t*3+tid]=r;
        }
    }
}

extern "C" void kernel_launch(void* const* d_in, const int* in_sizes, int n_in,
                              void* d_out, int out_size, void* d_ws, size_t ws_size,
                              hipStream_t stream) {
    const float* x     = (const float*)d_in[0];
    const float* W_x   = (const float*)d_in[1];
    const float* W_h   = (const float*)d_in[2];
    const float* b     = (const float*)d_in[3];
    const float* p_i   = (const float*)d_in[4];
    const float* p_f   = (const float*)d_in[5];
    const float* p_o   = (const float*)d_in[6];
    const float* W_out = (const float*)d_in[7];
    const float* b_out = (const float*)d_in[8];
    float* out = (float*)d_out;

    if (ws_size < WS_FULL) {
        lstm_fused_fb<<<BATCH, 512, 0, stream>>>(x, W_x, W_h, b, p_i, p_f, p_o,
                                                 W_out, b_out, out);
        return;
    }

    uint8_t* ws = (uint8_t*)d_ws;
    float* wbuf = (float*)(ws + WBUF_OFF);
    unsigned long long* hbuf = (unsigned long long*)(ws + HBUF_OFF);
    float* part = (float*)(ws + PART_OFF);

    hipMemsetAsync(hbuf, 0, HBUF_SZ, stream);    // kill stale tags (graph replay)
    reorder_w<<<(NBLK * UNITS * CPB + 255) / 256, 256, 0, stream>>>(W_h, wbuf);
    lstm_mb<<<NGRP * NBLK, 512, 0, stream>>>(x, W_x, b, p_i, p_f, p_o,
                                             W_out, wbuf, hbuf, part, out);
    finish_y<<<(BATCH * TLEN * 3 + 255) / 256, 256, 0, stream>>>(part, b_out, out);
}